// Round 2
// baseline (409.204 us; speedup 1.0000x reference)
//
#include <hip/hip_runtime.h>

#define NN 50000
#define NE 800000
#define NG 64

// ============================ CSR build ============================

__global__ void hist_kernel(const int* __restrict__ ei, int* __restrict__ deg) {
  int e = blockIdx.x * blockDim.x + threadIdx.x;
  if (e < NE) atomicAdd(&deg[ei[NE + e]], 1);
}

__global__ void scan1_kernel(const int* __restrict__ deg, int* __restrict__ rowptr,
                             int* __restrict__ bsums) {
  __shared__ int tile[256];
  int t = threadIdx.x, gid = blockIdx.x * 256 + t;
  int v = (gid < NN) ? deg[gid] : 0;
  tile[t] = v;
  __syncthreads();
  for (int off = 1; off < 256; off <<= 1) {
    int u = (t >= off) ? tile[t - off] : 0;
    __syncthreads();
    tile[t] += u;
    __syncthreads();
  }
  if (gid < NN) rowptr[gid] = tile[t] - v;  // exclusive within block
  if (t == 255) bsums[blockIdx.x] = tile[t];
}

__global__ void scan2_kernel(int* __restrict__ bsums, int nb) {
  __shared__ int tile[256];
  int t = threadIdx.x;
  int v = (t < nb) ? bsums[t] : 0;
  tile[t] = v;
  __syncthreads();
  for (int off = 1; off < 256; off <<= 1) {
    int u = (t >= off) ? tile[t - off] : 0;
    __syncthreads();
    tile[t] += u;
    __syncthreads();
  }
  if (t < nb) bsums[t] = tile[t] - v;  // exclusive
}

__global__ void scan3_kernel(int* __restrict__ rowptr, const int* __restrict__ bsums,
                             int* __restrict__ cursor) {
  int gid = blockIdx.x * 256 + threadIdx.x;
  if (gid < NN) {
    int r = rowptr[gid] + bsums[blockIdx.x];
    rowptr[gid] = r;
    cursor[gid] = r;
  } else if (gid == NN) {
    rowptr[NN] = NE;
  }
}

__global__ void scatter_kernel(const int* __restrict__ ei, int* __restrict__ cursor,
                               int* __restrict__ srcs) {
  int e = blockIdx.x * blockDim.x + threadIdx.x;
  if (e < NE) {
    int d = ei[NE + e];
    int pos = atomicAdd(&cursor[d], 1);
    srcs[pos] = ei[e];
  }
}

// ============================ node GEMMs ============================
// transform_dual: feat [NN,64] @ W [128,64] (two stacked 64x64 halves)
//   -> ab [NN,128]:  ab[n][c<64]  = sum_k feat[n][k]*W[k][c]        (dst half "a")
//                    ab[n][c>=64] = sum_k feat[n][k]*W[64+k][c-64]  (src half "b")
__global__ __launch_bounds__(256) void transform_dual(const float* __restrict__ feat,
                                                      const float* __restrict__ W,
                                                      float* __restrict__ ab) {
  __shared__ __attribute__((aligned(16))) float xs[64 * 64];
  __shared__ __attribute__((aligned(16))) float wst[128 * 68];  // transposed, padded
  int t = threadIdx.x;
  int nodebase = blockIdx.x * 64;

  // load 64 node rows (float4, coalesced)
  {
    const float4* f4 = reinterpret_cast<const float4*>(feat);
    float4* x4 = reinterpret_cast<float4*>(xs);
    for (int j = 0; j < 4; ++j) {
      int idx4 = j * 256 + t;  // 0..1023, 16 float4 per node row
      int node = nodebase + (idx4 >> 4);
      float4 v = make_float4(0.f, 0.f, 0.f, 0.f);
      if (node < NN) v = f4[(size_t)nodebase * 16 + idx4];
      x4[idx4] = v;
    }
  }
  // load W transposed: wst[c*68+k] = W[(c>=64)*4096 + k*64 + (c&63)]
  {
    int c = t & 127;
    int half = t >> 7;
    int cc = c & 63;
    int base = (c >= 64) ? 4096 : 0;
    for (int kk = half * 32; kk < half * 32 + 32; ++kk)
      wst[c * 68 + kk] = W[base + kk * 64 + cc];
  }
  __syncthreads();

  int col = t & 127;
  int ng = t >> 7;  // 0/1
  float acc[32];
#pragma unroll
  for (int i = 0; i < 32; ++i) acc[i] = 0.f;

  const float4* w4 = reinterpret_cast<const float4*>(&wst[col * 68]);
#pragma unroll 4
  for (int k4 = 0; k4 < 16; ++k4) {
    float4 w = w4[k4];
#pragma unroll
    for (int i = 0; i < 32; ++i) {
      float4 xv = *reinterpret_cast<const float4*>(&xs[(2 * i + ng) * 64 + 4 * k4]);
      acc[i] += w.x * xv.x + w.y * xv.y + w.z * xv.z + w.w * xv.w;
    }
  }

#pragma unroll
  for (int i = 0; i < 32; ++i) {
    int node = nodebase + 2 * i + ng;
    if (node < NN) ab[(size_t)node * 128 + col] = acc[i];
  }
}

// transform_single: agg [NN,64] @ W2 [64,64], + cnt*b2, outer relu -> out [NN,64]
// NOTE: out may alias feat (all reads staged to LDS before any write).
__global__ __launch_bounds__(256) void transform_single(const float* __restrict__ feat,
                                                        const float* __restrict__ W,
                                                        const float* __restrict__ bias,
                                                        const int* __restrict__ deg,
                                                        float* __restrict__ out) {
  __shared__ __attribute__((aligned(16))) float xs[64 * 64];
  __shared__ __attribute__((aligned(16))) float wst[64 * 68];
  int t = threadIdx.x;
  int nodebase = blockIdx.x * 64;

  {
    const float4* f4 = reinterpret_cast<const float4*>(feat);
    float4* x4 = reinterpret_cast<float4*>(xs);
    for (int j = 0; j < 4; ++j) {
      int idx4 = j * 256 + t;
      int node = nodebase + (idx4 >> 4);
      float4 v = make_float4(0.f, 0.f, 0.f, 0.f);
      if (node < NN) v = f4[(size_t)nodebase * 16 + idx4];
      x4[idx4] = v;
    }
  }
  {
    int c = t & 63;
    int q = t >> 6;  // 0..3
    for (int kk = q * 16; kk < q * 16 + 16; ++kk)
      wst[c * 68 + kk] = W[kk * 64 + c];
  }
  __syncthreads();

  int col = t & 63;
  int ng = t >> 6;  // 0..3
  float acc[16];
#pragma unroll
  for (int i = 0; i < 16; ++i) acc[i] = 0.f;

  const float4* w4 = reinterpret_cast<const float4*>(&wst[col * 68]);
#pragma unroll 4
  for (int k4 = 0; k4 < 16; ++k4) {
    float4 w = w4[k4];
#pragma unroll
    for (int i = 0; i < 16; ++i) {
      float4 xv = *reinterpret_cast<const float4*>(&xs[(4 * i + ng) * 64 + 4 * k4]);
      acc[i] += w.x * xv.x + w.y * xv.y + w.z * xv.z + w.w * xv.w;
    }
  }

  float bv = bias[col];
#pragma unroll
  for (int i = 0; i < 16; ++i) {
    int node = nodebase + 4 * i + ng;
    if (node < NN) {
      float cnt = (float)(deg[node] + 1);  // + self loop
      out[(size_t)node * 64 + col] = fmaxf(acc[i] + cnt * bv, 0.f);
    }
  }
}

// ============================ edge aggregation ============================
// agg[n][c] = sum over incoming edges (incl. self loop) of relu(a[n][c]+b[src][c]+b1[c])
__global__ __launch_bounds__(256) void edge_agg(const float* __restrict__ ab,
                                                const int* __restrict__ rowptr,
                                                const int* __restrict__ srcs,
                                                const float* __restrict__ b1,
                                                float* __restrict__ agg) {
  int node = blockIdx.x * 4 + (threadIdx.x >> 6);
  int lane = threadIdx.x & 63;
  if (node >= NN) return;
  float an = ab[(size_t)node * 128 + lane] + b1[lane];
  float acc = fmaxf(an + ab[(size_t)node * 128 + 64 + lane], 0.f);  // self loop
  int s0 = rowptr[node], s1 = rowptr[node + 1];
  for (int eb = s0; eb < s1; eb += 64) {
    int m = s1 - eb;
    if (m > 64) m = 64;
    int sid = (lane < m) ? srcs[eb + lane] : 0;
    for (int j = 0; j < m; ++j) {
      int s = __shfl(sid, j);
      acc += fmaxf(an + ab[(size_t)s * 128 + 64 + lane], 0.f);
    }
  }
  agg[(size_t)node * 64 + lane] = acc;
}

// ============================ pooling + head ============================

__global__ void pool_kernel(const float* __restrict__ h, const int* __restrict__ batch,
                            float* __restrict__ pooled, float* __restrict__ cntf) {
  int lane = threadIdx.x;  // 64
  int start = blockIdx.x * 256;
  int end = start + 256;
  if (end > NN) end = NN;
  int gcur = -1;
  float acc = 0.f, c = 0.f;
  for (int n = start; n < end; ++n) {
    int g = batch[n];
    if (g != gcur) {
      if (gcur >= 0) {
        atomicAdd(&pooled[gcur * 64 + lane], acc);
        if (lane == 0) atomicAdd(&cntf[gcur], c);
      }
      gcur = g;
      acc = 0.f;
      c = 0.f;
    }
    acc += h[(size_t)n * 64 + lane];
    c += 1.f;
  }
  if (gcur >= 0) {
    atomicAdd(&pooled[gcur * 64 + lane], acc);
    if (lane == 0) atomicAdd(&cntf[gcur], c);
  }
}

__global__ void final_kernel(const float* __restrict__ pooled, const float* __restrict__ cntf,
                             const float* __restrict__ Wl, const float* __restrict__ bl,
                             float* __restrict__ out) {
  int idx = blockIdx.x * 256 + threadIdx.x;  // 0..4095
  int g = idx >> 6, o = idx & 63;
  float inv = 1.f / fmaxf(cntf[g], 1.f);
  float acc = bl[o];
  for (int k = 0; k < 64; ++k) acc += pooled[g * 64 + k] * inv * Wl[k * 64 + o];
  out[idx] = acc;
}

// ============================ launch ============================

extern "C" void kernel_launch(void* const* d_in, const int* in_sizes, int n_in,
                              void* d_out, int out_size, void* d_ws, size_t ws_size,
                              hipStream_t stream) {
  const float* x = (const float*)d_in[0];
  const int* ei = (const int*)d_in[1];     // int32 per harness contract, [2, NE]
  const int* batch = (const int*)d_in[2];  // int32
  const float* W1a = (const float*)d_in[3];
  const float* b1a = (const float*)d_in[4];
  const float* W2a = (const float*)d_in[5];
  const float* b2a = (const float*)d_in[6];
  const float* W1b = (const float*)d_in[7];
  const float* b1b = (const float*)d_in[8];
  const float* W2b = (const float*)d_in[9];
  const float* b2b = (const float*)d_in[10];
  const float* Wl = (const float*)d_in[11];
  const float* bl = (const float*)d_in[12];
  float* out = (float*)d_out;

  char* p = (char*)d_ws;
  auto alloc = [&](size_t bytes) {
    char* r = p;
    p += (bytes + 255) & ~(size_t)255;
    return r;
  };
  int* deg = (int*)alloc((NN + 1) * sizeof(int));
  int* rowptr = (int*)alloc((NN + 1) * sizeof(int));
  int* cursor = (int*)alloc(NN * sizeof(int));
  int* bsums = (int*)alloc(256 * sizeof(int));
  int* srcs = (int*)alloc((size_t)NE * sizeof(int));
  float* ab = (float*)alloc((size_t)NN * 128 * sizeof(float));
  float* hbuf = (float*)alloc((size_t)NN * 64 * sizeof(float));  // agg and h alias
  float* pooled = (float*)alloc(NG * 64 * sizeof(float));
  float* cntf = (float*)alloc(NG * sizeof(float));

  hipMemsetAsync(deg, 0, (NN + 1) * sizeof(int), stream);
  hipMemsetAsync(pooled, 0, NG * 64 * sizeof(float), stream);
  hipMemsetAsync(cntf, 0, NG * sizeof(float), stream);

  hist_kernel<<<(NE + 255) / 256, 256, 0, stream>>>(ei, deg);
  scan1_kernel<<<196, 256, 0, stream>>>(deg, rowptr, bsums);
  scan2_kernel<<<1, 256, 0, stream>>>(bsums, 196);
  scan3_kernel<<<196, 256, 0, stream>>>(rowptr, bsums, cursor);
  scatter_kernel<<<(NE + 255) / 256, 256, 0, stream>>>(ei, cursor, srcs);

  int tb = (NN + 63) / 64;  // 782
  // layer 1
  transform_dual<<<tb, 256, 0, stream>>>(x, W1a, ab);
  edge_agg<<<(NN + 3) / 4, 256, 0, stream>>>(ab, rowptr, srcs, b1a, hbuf);
  transform_single<<<tb, 256, 0, stream>>>(hbuf, W2a, b2a, deg, hbuf);
  // layer 2
  transform_dual<<<tb, 256, 0, stream>>>(hbuf, W1b, ab);
  edge_agg<<<(NN + 3) / 4, 256, 0, stream>>>(ab, rowptr, srcs, b1b, hbuf);
  transform_single<<<tb, 256, 0, stream>>>(hbuf, W2b, b2b, deg, hbuf);
  // pool + head
  pool_kernel<<<(NN + 255) / 256, 64, 0, stream>>>(hbuf, batch, pooled, cntf);
  final_kernel<<<16, 256, 0, stream>>>(pooled, cntf, Wl, bl, out);
}

// Round 3
// 312.906 us; speedup vs baseline: 1.3078x; 1.3078x over previous
//
#include <hip/hip_runtime.h>

#define NN 50000
#define NE 800000
#define NG 64

// ============================ CSR build ============================

__global__ void hist_kernel(const int* __restrict__ ei, int* __restrict__ deg) {
  int e = blockIdx.x * blockDim.x + threadIdx.x;
  if (e < NE) atomicAdd(&deg[ei[NE + e]], 1);
}

__global__ void scan1_kernel(const int* __restrict__ deg, int* __restrict__ rowptr,
                             int* __restrict__ bsums) {
  __shared__ int tile[256];
  int t = threadIdx.x, gid = blockIdx.x * 256 + t;
  int v = (gid < NN) ? deg[gid] : 0;
  tile[t] = v;
  __syncthreads();
  for (int off = 1; off < 256; off <<= 1) {
    int u = (t >= off) ? tile[t - off] : 0;
    __syncthreads();
    tile[t] += u;
    __syncthreads();
  }
  if (gid < NN) rowptr[gid] = tile[t] - v;  // exclusive within block
  if (t == 255) bsums[blockIdx.x] = tile[t];
}

__global__ void scan2_kernel(int* __restrict__ bsums, int nb) {
  __shared__ int tile[256];
  int t = threadIdx.x;
  int v = (t < nb) ? bsums[t] : 0;
  tile[t] = v;
  __syncthreads();
  for (int off = 1; off < 256; off <<= 1) {
    int u = (t >= off) ? tile[t - off] : 0;
    __syncthreads();
    tile[t] += u;
    __syncthreads();
  }
  if (t < nb) bsums[t] = tile[t] - v;  // exclusive
}

__global__ void scan3_kernel(int* __restrict__ rowptr, const int* __restrict__ bsums,
                             int* __restrict__ cursor) {
  int gid = blockIdx.x * 256 + threadIdx.x;
  if (gid < NN) {
    int r = rowptr[gid] + bsums[blockIdx.x];
    rowptr[gid] = r;
    cursor[gid] = r;
  } else if (gid == NN) {
    rowptr[NN] = NE;
  }
}

__global__ void scatter_kernel(const int* __restrict__ ei, int* __restrict__ cursor,
                               int* __restrict__ srcs) {
  int e = blockIdx.x * blockDim.x + threadIdx.x;
  if (e < NE) {
    int d = ei[NE + e];
    int pos = atomicAdd(&cursor[d], 1);
    srcs[pos] = ei[e];
  }
}

// ============================ node GEMMs ============================

__global__ __launch_bounds__(256) void transform_dual(const float* __restrict__ feat,
                                                      const float* __restrict__ W,
                                                      float* __restrict__ ab) {
  __shared__ __attribute__((aligned(16))) float xs[64 * 64];
  __shared__ __attribute__((aligned(16))) float wst[128 * 68];  // transposed, padded
  int t = threadIdx.x;
  int nodebase = blockIdx.x * 64;

  {
    const float4* f4 = reinterpret_cast<const float4*>(feat);
    float4* x4 = reinterpret_cast<float4*>(xs);
    for (int j = 0; j < 4; ++j) {
      int idx4 = j * 256 + t;  // 0..1023, 16 float4 per node row
      int node = nodebase + (idx4 >> 4);
      float4 v = make_float4(0.f, 0.f, 0.f, 0.f);
      if (node < NN) v = f4[(size_t)nodebase * 16 + idx4];
      x4[idx4] = v;
    }
  }
  {
    int c = t & 127;
    int half = t >> 7;
    int cc = c & 63;
    int base = (c >= 64) ? 4096 : 0;
    for (int kk = half * 32; kk < half * 32 + 32; ++kk)
      wst[c * 68 + kk] = W[base + kk * 64 + cc];
  }
  __syncthreads();

  int col = t & 127;
  int ng = t >> 7;  // 0/1
  float acc[32];
#pragma unroll
  for (int i = 0; i < 32; ++i) acc[i] = 0.f;

  const float4* w4 = reinterpret_cast<const float4*>(&wst[col * 68]);
#pragma unroll 4
  for (int k4 = 0; k4 < 16; ++k4) {
    float4 w = w4[k4];
#pragma unroll
    for (int i = 0; i < 32; ++i) {
      float4 xv = *reinterpret_cast<const float4*>(&xs[(2 * i + ng) * 64 + 4 * k4]);
      acc[i] += w.x * xv.x + w.y * xv.y + w.z * xv.z + w.w * xv.w;
    }
  }

#pragma unroll
  for (int i = 0; i < 32; ++i) {
    int node = nodebase + 2 * i + ng;
    if (node < NN) ab[(size_t)node * 128 + col] = acc[i];
  }
}

// transform_single: agg [NN,64] @ W2 [64,64], + cnt*b2, outer relu -> out [NN,64]
// out may alias feat (all reads staged to LDS behind a barrier).
__global__ __launch_bounds__(256) void transform_single(const float* __restrict__ feat,
                                                        const float* __restrict__ W,
                                                        const float* __restrict__ bias,
                                                        const int* __restrict__ deg,
                                                        float* __restrict__ out) {
  __shared__ __attribute__((aligned(16))) float xs[64 * 64];
  __shared__ __attribute__((aligned(16))) float wst[64 * 68];
  int t = threadIdx.x;
  int nodebase = blockIdx.x * 64;

  {
    const float4* f4 = reinterpret_cast<const float4*>(feat);
    float4* x4 = reinterpret_cast<float4*>(xs);
    for (int j = 0; j < 4; ++j) {
      int idx4 = j * 256 + t;
      int node = nodebase + (idx4 >> 4);
      float4 v = make_float4(0.f, 0.f, 0.f, 0.f);
      if (node < NN) v = f4[(size_t)nodebase * 16 + idx4];
      x4[idx4] = v;
    }
  }
  {
    int c = t & 63;
    int q = t >> 6;  // 0..3
    for (int kk = q * 16; kk < q * 16 + 16; ++kk)
      wst[c * 68 + kk] = W[kk * 64 + c];
  }
  __syncthreads();

  int col = t & 63;
  int ng = t >> 6;  // 0..3
  float acc[16];
#pragma unroll
  for (int i = 0; i < 16; ++i) acc[i] = 0.f;

  const float4* w4 = reinterpret_cast<const float4*>(&wst[col * 68]);
#pragma unroll 4
  for (int k4 = 0; k4 < 16; ++k4) {
    float4 w = w4[k4];
#pragma unroll
    for (int i = 0; i < 16; ++i) {
      float4 xv = *reinterpret_cast<const float4*>(&xs[(4 * i + ng) * 64 + 4 * k4]);
      acc[i] += w.x * xv.x + w.y * xv.y + w.z * xv.z + w.w * xv.w;
    }
  }

  float bv = bias[col];
#pragma unroll
  for (int i = 0; i < 16; ++i) {
    int node = nodebase + 4 * i + ng;
    if (node < NN) {
      float cnt = (float)(deg[node] + 1);  // + self loop
      out[(size_t)node * 64 + col] = fmaxf(acc[i] + cnt * bv, 0.f);
    }
  }
}

// ============================ edge aggregation ============================
// agg[n][c] = sum over in-edges (incl. self loop) of relu(a[n][c]+b[src][c]+b1[c])
// Wave layout: 4 edge-slots x 16 lanes; each lane holds 4 channels as float4.
__device__ __forceinline__ float4 relu4(float4 v) {
  return make_float4(fmaxf(v.x, 0.f), fmaxf(v.y, 0.f), fmaxf(v.z, 0.f), fmaxf(v.w, 0.f));
}

__global__ __launch_bounds__(256) void edge_agg(const float* __restrict__ ab,
                                                const int* __restrict__ rowptr,
                                                const int* __restrict__ srcs,
                                                const float* __restrict__ b1,
                                                float* __restrict__ agg) {
  int node = blockIdx.x * 4 + (threadIdx.x >> 6);
  if (node >= NN) return;
  int lane = threadIdx.x & 63;
  int slot = lane >> 4;  // 0..3
  int c16 = lane & 15;   // float4 channel index

  const float4* ab4 = reinterpret_cast<const float4*>(ab);
  const float4* b14 = reinterpret_cast<const float4*>(b1);

  float4 an = ab4[(size_t)node * 32 + c16];
  float4 bb = b14[c16];
  an.x += bb.x; an.y += bb.y; an.z += bb.z; an.w += bb.w;

  float4 acc = make_float4(0.f, 0.f, 0.f, 0.f);
  if (slot == 0) {  // self loop once
    float4 bs = ab4[(size_t)node * 32 + 16 + c16];
    acc = relu4(make_float4(an.x + bs.x, an.y + bs.y, an.z + bs.z, an.w + bs.w));
  }

  int s0 = rowptr[node], s1 = rowptr[node + 1];
  for (int e = s0 + slot; e < s1; e += 4) {
    int s = srcs[e];  // 16 lanes same addr -> broadcast
    float4 bs = ab4[(size_t)s * 32 + 16 + c16];
    float4 m = relu4(make_float4(an.x + bs.x, an.y + bs.y, an.z + bs.z, an.w + bs.w));
    acc.x += m.x; acc.y += m.y; acc.z += m.z; acc.w += m.w;
  }

  // fold the 4 slots (butterfly over lane bits 4,5)
#pragma unroll
  for (int m = 16; m <= 32; m <<= 1) {
    acc.x += __shfl_xor(acc.x, m, 64);
    acc.y += __shfl_xor(acc.y, m, 64);
    acc.z += __shfl_xor(acc.z, m, 64);
    acc.w += __shfl_xor(acc.w, m, 64);
  }
  if (slot == 0) {
    float4* agg4 = reinterpret_cast<float4*>(agg);
    agg4[(size_t)node * 16 + c16] = acc;
  }
}

// ============================ pooling + head ============================

__global__ void gstart_kernel(const int* __restrict__ batch, int* __restrict__ gstart) {
  int g = threadIdx.x;
  if (g > NG) return;
  int lo = 0, hi = NN;
  while (lo < hi) {
    int mid = (lo + hi) >> 1;
    if (batch[mid] < g) lo = mid + 1; else hi = mid;
  }
  gstart[g] = lo;
}

__global__ __launch_bounds__(512) void pool_kernel(const float* __restrict__ h,
                                                   const int* __restrict__ gstart,
                                                   float* __restrict__ pooled) {
  int g = blockIdx.x;
  int t = threadIdx.x;
  int lane = t & 63, w = t >> 6;  // 8 waves
  int s = gstart[g], e = gstart[g + 1];
  float a0 = 0.f, a1 = 0.f;
  int n = s + w;
  for (; n + 8 < e; n += 16) {
    a0 += h[(size_t)n * 64 + lane];
    a1 += h[(size_t)(n + 8) * 64 + lane];
  }
  for (; n < e; n += 8) a0 += h[(size_t)n * 64 + lane];
  __shared__ float red[8][64];
  red[w][lane] = a0 + a1;
  __syncthreads();
  if (w == 0) {
    float sum = 0.f;
#pragma unroll
    for (int i = 0; i < 8; ++i) sum += red[i][lane];
    float cnt = (float)(e - s);
    pooled[g * 64 + lane] = sum / fmaxf(cnt, 1.f);  // mean
  }
}

__global__ void final_kernel(const float* __restrict__ pm, const float* __restrict__ Wl,
                             const float* __restrict__ bl, float* __restrict__ out) {
  int idx = blockIdx.x * 256 + threadIdx.x;  // 0..4095
  int g = idx >> 6, o = idx & 63;
  float acc = bl[o];
  for (int k = 0; k < 64; ++k) acc += pm[g * 64 + k] * Wl[k * 64 + o];
  out[idx] = acc;
}

// ============================ launch ============================

extern "C" void kernel_launch(void* const* d_in, const int* in_sizes, int n_in,
                              void* d_out, int out_size, void* d_ws, size_t ws_size,
                              hipStream_t stream) {
  const float* x = (const float*)d_in[0];
  const int* ei = (const int*)d_in[1];     // int32, [2, NE]
  const int* batch = (const int*)d_in[2];  // int32, sorted
  const float* W1a = (const float*)d_in[3];
  const float* b1a = (const float*)d_in[4];
  const float* W2a = (const float*)d_in[5];
  const float* b2a = (const float*)d_in[6];
  const float* W1b = (const float*)d_in[7];
  const float* b1b = (const float*)d_in[8];
  const float* W2b = (const float*)d_in[9];
  const float* b2b = (const float*)d_in[10];
  const float* Wl = (const float*)d_in[11];
  const float* bl = (const float*)d_in[12];
  float* out = (float*)d_out;

  char* p = (char*)d_ws;
  auto alloc = [&](size_t bytes) {
    char* r = p;
    p += (bytes + 255) & ~(size_t)255;
    return r;
  };
  int* deg = (int*)alloc((NN + 1) * sizeof(int));
  int* rowptr = (int*)alloc((NN + 1) * sizeof(int));
  int* cursor = (int*)alloc(NN * sizeof(int));
  int* bsums = (int*)alloc(256 * sizeof(int));
  int* gstart = (int*)alloc((NG + 1) * sizeof(int));
  int* srcs = (int*)alloc((size_t)NE * sizeof(int));
  float* ab = (float*)alloc((size_t)NN * 128 * sizeof(float));
  float* hbuf = (float*)alloc((size_t)NN * 64 * sizeof(float));  // agg and h alias
  float* pooled = (float*)alloc(NG * 64 * sizeof(float));

  hipMemsetAsync(deg, 0, (NN + 1) * sizeof(int), stream);

  hist_kernel<<<(NE + 255) / 256, 256, 0, stream>>>(ei, deg);
  scan1_kernel<<<196, 256, 0, stream>>>(deg, rowptr, bsums);
  scan2_kernel<<<1, 256, 0, stream>>>(bsums, 196);
  scan3_kernel<<<196, 256, 0, stream>>>(rowptr, bsums, cursor);
  scatter_kernel<<<(NE + 255) / 256, 256, 0, stream>>>(ei, cursor, srcs);
  gstart_kernel<<<1, 128, 0, stream>>>(batch, gstart);

  int tb = (NN + 63) / 64;  // 782
  // layer 1
  transform_dual<<<tb, 256, 0, stream>>>(x, W1a, ab);
  edge_agg<<<(NN + 3) / 4, 256, 0, stream>>>(ab, rowptr, srcs, b1a, hbuf);
  transform_single<<<tb, 256, 0, stream>>>(hbuf, W2a, b2a, deg, hbuf);
  // layer 2
  transform_dual<<<tb, 256, 0, stream>>>(hbuf, W1b, ab);
  edge_agg<<<(NN + 3) / 4, 256, 0, stream>>>(ab, rowptr, srcs, b1b, hbuf);
  transform_single<<<tb, 256, 0, stream>>>(hbuf, W2b, b2b, deg, hbuf);
  // pool + head
  pool_kernel<<<NG, 512, 0, stream>>>(hbuf, gstart, pooled);
  final_kernel<<<16, 256, 0, stream>>>(pooled, Wl, bl, out);
}

// Round 4
// 291.086 us; speedup vs baseline: 1.4058x; 1.0750x over previous
//
#include <hip/hip_runtime.h>

#define NN 50000
#define NE 800000
#define NG 64
#define NXCD 8
#define DPART (NN / NXCD)  // 6250

// ============================ CSR build ============================

__global__ void hist_kernel(const int* __restrict__ ei, int* __restrict__ deg) {
  int e = blockIdx.x * blockDim.x + threadIdx.x;
  if (e < NE) atomicAdd(&deg[ei[NE + e]], 1);
}

__global__ void scan1_kernel(const int* __restrict__ deg, int* __restrict__ rowptr,
                             int* __restrict__ bsums) {
  __shared__ int tile[256];
  int t = threadIdx.x, gid = blockIdx.x * 256 + t;
  int v = (gid < NN) ? deg[gid] : 0;
  tile[t] = v;
  __syncthreads();
  for (int off = 1; off < 256; off <<= 1) {
    int u = (t >= off) ? tile[t - off] : 0;
    __syncthreads();
    tile[t] += u;
    __syncthreads();
  }
  if (gid < NN) rowptr[gid] = tile[t] - v;  // exclusive within block
  if (t == 255) bsums[blockIdx.x] = tile[t];
}

__global__ void scan2_kernel(int* __restrict__ bsums, int nb) {
  __shared__ int tile[256];
  int t = threadIdx.x;
  int v = (t < nb) ? bsums[t] : 0;
  tile[t] = v;
  __syncthreads();
  for (int off = 1; off < 256; off <<= 1) {
    int u = (t >= off) ? tile[t - off] : 0;
    __syncthreads();
    tile[t] += u;
    __syncthreads();
  }
  if (t < nb) bsums[t] = tile[t] - v;  // exclusive
}

__global__ void scan3_kernel(int* __restrict__ rowptr, const int* __restrict__ bsums,
                             int* __restrict__ cursor) {
  int gid = blockIdx.x * 256 + threadIdx.x;
  if (gid < NN) {
    int r = rowptr[gid] + bsums[blockIdx.x];
    rowptr[gid] = r;
    cursor[gid] = r;
  } else if (gid == NN) {
    rowptr[NN] = NE;
  }
}

// XCD-partitioned scatter: group g = blockIdx&7 handles dst in [g*DPART,(g+1)*DPART).
// With round-robin block->XCD dispatch, each srcs region is written by one XCD only
// -> lines fill in that XCD's L2, ~1x writeback instead of 16x write amplification.
// Correct under ANY block->XCD mapping (only locality is heuristic).
__global__ __launch_bounds__(256) void scatter_xcd(const int* __restrict__ ei,
                                                   int* __restrict__ cursor,
                                                   int* __restrict__ srcs) {
  int g = blockIdx.x & 7;
  int bid = blockIdx.x >> 3;
  int nb = gridDim.x >> 3;
  int lo = g * DPART, hi = lo + DPART;
  int stride = nb * 256;
  for (int e = bid * 256 + threadIdx.x; e < NE; e += stride) {
    int d = ei[NE + e];
    if (d >= lo && d < hi) {
      int pos = atomicAdd(&cursor[d], 1);
      srcs[pos] = ei[e];
    }
  }
}

// ============================ node GEMMs ============================

__global__ __launch_bounds__(256) void transform_dual(const float* __restrict__ feat,
                                                      const float* __restrict__ W,
                                                      float* __restrict__ ab) {
  __shared__ __attribute__((aligned(16))) float xs[64 * 64];
  __shared__ __attribute__((aligned(16))) float wst[128 * 68];  // transposed, padded
  int t = threadIdx.x;
  int nodebase = blockIdx.x * 64;

  {
    const float4* f4 = reinterpret_cast<const float4*>(feat);
    float4* x4 = reinterpret_cast<float4*>(xs);
    for (int j = 0; j < 4; ++j) {
      int idx4 = j * 256 + t;  // 0..1023, 16 float4 per node row
      int node = nodebase + (idx4 >> 4);
      float4 v = make_float4(0.f, 0.f, 0.f, 0.f);
      if (node < NN) v = f4[(size_t)nodebase * 16 + idx4];
      x4[idx4] = v;
    }
  }
  {
    int c = t & 127;
    int half = t >> 7;
    int cc = c & 63;
    int base = (c >= 64) ? 4096 : 0;
    for (int kk = half * 32; kk < half * 32 + 32; ++kk)
      wst[c * 68 + kk] = W[base + kk * 64 + cc];
  }
  __syncthreads();

  int col = t & 127;
  int ng = t >> 7;  // 0/1
  float acc[32];
#pragma unroll
  for (int i = 0; i < 32; ++i) acc[i] = 0.f;

  const float4* w4 = reinterpret_cast<const float4*>(&wst[col * 68]);
#pragma unroll 4
  for (int k4 = 0; k4 < 16; ++k4) {
    float4 w = w4[k4];
#pragma unroll
    for (int i = 0; i < 32; ++i) {
      float4 xv = *reinterpret_cast<const float4*>(&xs[(2 * i + ng) * 64 + 4 * k4]);
      acc[i] += w.x * xv.x + w.y * xv.y + w.z * xv.z + w.w * xv.w;
    }
  }

#pragma unroll
  for (int i = 0; i < 32; ++i) {
    int node = nodebase + 2 * i + ng;
    if (node < NN) ab[(size_t)node * 128 + col] = acc[i];
  }
}

// transform_single: agg [NN,64] @ W2 [64,64], + cnt*b2, outer relu -> out [NN,64]
// out may alias feat (all reads staged to LDS behind a barrier).
__global__ __launch_bounds__(256) void transform_single(const float* __restrict__ feat,
                                                        const float* __restrict__ W,
                                                        const float* __restrict__ bias,
                                                        const int* __restrict__ deg,
                                                        float* __restrict__ out) {
  __shared__ __attribute__((aligned(16))) float xs[64 * 64];
  __shared__ __attribute__((aligned(16))) float wst[64 * 68];
  int t = threadIdx.x;
  int nodebase = blockIdx.x * 64;

  {
    const float4* f4 = reinterpret_cast<const float4*>(feat);
    float4* x4 = reinterpret_cast<float4*>(xs);
    for (int j = 0; j < 4; ++j) {
      int idx4 = j * 256 + t;
      int node = nodebase + (idx4 >> 4);
      float4 v = make_float4(0.f, 0.f, 0.f, 0.f);
      if (node < NN) v = f4[(size_t)nodebase * 16 + idx4];
      x4[idx4] = v;
    }
  }
  {
    int c = t & 63;
    int q = t >> 6;  // 0..3
    for (int kk = q * 16; kk < q * 16 + 16; ++kk)
      wst[c * 68 + kk] = W[kk * 64 + c];
  }
  __syncthreads();

  int col = t & 63;
  int ng = t >> 6;  // 0..3
  float acc[16];
#pragma unroll
  for (int i = 0; i < 16; ++i) acc[i] = 0.f;

  const float4* w4 = reinterpret_cast<const float4*>(&wst[col * 68]);
#pragma unroll 4
  for (int k4 = 0; k4 < 16; ++k4) {
    float4 w = w4[k4];
#pragma unroll
    for (int i = 0; i < 16; ++i) {
      float4 xv = *reinterpret_cast<const float4*>(&xs[(4 * i + ng) * 64 + 4 * k4]);
      acc[i] += w.x * xv.x + w.y * xv.y + w.z * xv.z + w.w * xv.w;
    }
  }

  float bv = bias[col];
#pragma unroll
  for (int i = 0; i < 16; ++i) {
    int node = nodebase + 4 * i + ng;
    if (node < NN) {
      float cnt = (float)(deg[node] + 1);  // + self loop
      out[(size_t)node * 64 + col] = fmaxf(acc[i] + cnt * bv, 0.f);
    }
  }
}

// ============================ edge aggregation ============================
// agg[n][c] = sum over in-edges (incl. self loop) of relu(a[n][c]+b[src][c]+b1[c])
// Wave layout: 8 edge-slots x 8 lanes; each lane holds 8 channels (2x float4).
__device__ __forceinline__ float4 relu4(float4 v) {
  return make_float4(fmaxf(v.x, 0.f), fmaxf(v.y, 0.f), fmaxf(v.z, 0.f), fmaxf(v.w, 0.f));
}
__device__ __forceinline__ float4 add4(float4 a, float4 b) {
  return make_float4(a.x + b.x, a.y + b.y, a.z + b.z, a.w + b.w);
}

__global__ __launch_bounds__(256) void edge_agg(const float* __restrict__ ab,
                                                const int* __restrict__ rowptr,
                                                const int* __restrict__ srcs,
                                                const float* __restrict__ b1,
                                                float* __restrict__ agg) {
  int node = blockIdx.x * 4 + (threadIdx.x >> 6);
  if (node >= NN) return;
  int lane = threadIdx.x & 63;
  int slot = lane >> 3;  // 0..7
  int c8 = lane & 7;     // 32B chunk index within the 256B row

  const float4* ab4 = reinterpret_cast<const float4*>(ab);
  const float4* b14 = reinterpret_cast<const float4*>(b1);

  float4 an0 = add4(ab4[(size_t)node * 32 + c8 * 2], b14[c8 * 2]);
  float4 an1 = add4(ab4[(size_t)node * 32 + c8 * 2 + 1], b14[c8 * 2 + 1]);

  float4 acc0 = make_float4(0.f, 0.f, 0.f, 0.f);
  float4 acc1 = make_float4(0.f, 0.f, 0.f, 0.f);
  if (slot == 0) {  // self loop once
    acc0 = relu4(add4(an0, ab4[(size_t)node * 32 + 16 + c8 * 2]));
    acc1 = relu4(add4(an1, ab4[(size_t)node * 32 + 16 + c8 * 2 + 1]));
  }

  int s0 = rowptr[node], s1 = rowptr[node + 1];
  for (int e = s0 + slot; e < s1; e += 8) {
    int s = srcs[e];
    float4 m0 = relu4(add4(an0, ab4[(size_t)s * 32 + 16 + c8 * 2]));
    float4 m1 = relu4(add4(an1, ab4[(size_t)s * 32 + 16 + c8 * 2 + 1]));
    acc0 = add4(acc0, m0);
    acc1 = add4(acc1, m1);
  }

  // fold the 8 slots (butterfly over lane bits 3,4,5)
#pragma unroll
  for (int m = 8; m <= 32; m <<= 1) {
    acc0.x += __shfl_xor(acc0.x, m, 64);
    acc0.y += __shfl_xor(acc0.y, m, 64);
    acc0.z += __shfl_xor(acc0.z, m, 64);
    acc0.w += __shfl_xor(acc0.w, m, 64);
    acc1.x += __shfl_xor(acc1.x, m, 64);
    acc1.y += __shfl_xor(acc1.y, m, 64);
    acc1.z += __shfl_xor(acc1.z, m, 64);
    acc1.w += __shfl_xor(acc1.w, m, 64);
  }
  if (slot == 0) {
    float4* agg4 = reinterpret_cast<float4*>(agg);
    agg4[(size_t)node * 16 + c8 * 2] = acc0;
    agg4[(size_t)node * 16 + c8 * 2 + 1] = acc1;
  }
}

// ============================ pooling + head ============================

__global__ void gstart_kernel(const int* __restrict__ batch, int* __restrict__ gstart) {
  int g = threadIdx.x;
  if (g > NG) return;
  int lo = 0, hi = NN;
  while (lo < hi) {
    int mid = (lo + hi) >> 1;
    if (batch[mid] < g) lo = mid + 1; else hi = mid;
  }
  gstart[g] = lo;
}

// 4 blocks per graph, partial sums via atomics (pooled must be zeroed).
__global__ __launch_bounds__(256) void pool_kernel(const float* __restrict__ h,
                                                   const int* __restrict__ gstart,
                                                   float* __restrict__ pooled) {
  int g = blockIdx.x >> 2, q = blockIdx.x & 3;
  int lane = threadIdx.x & 63, w = threadIdx.x >> 6;  // 4 waves
  int s = gstart[g], e = gstart[g + 1];
  int len = e - s;
  int qs = s + (len * q) / 4, qe = s + (len * (q + 1)) / 4;
  float a0 = 0.f, a1 = 0.f;
  int n = qs + w;
  for (; n + 4 < qe; n += 8) {
    a0 += h[(size_t)n * 64 + lane];
    a1 += h[(size_t)(n + 4) * 64 + lane];
  }
  for (; n < qe; n += 4) a0 += h[(size_t)n * 64 + lane];
  __shared__ float red[4][64];
  red[w][lane] = a0 + a1;
  __syncthreads();
  if (w == 0) {
    float sum = red[0][lane] + red[1][lane] + red[2][lane] + red[3][lane];
    atomicAdd(&pooled[g * 64 + lane], sum);
  }
}

__global__ void final_kernel(const float* __restrict__ pooled, const int* __restrict__ gstart,
                             const float* __restrict__ Wl, const float* __restrict__ bl,
                             float* __restrict__ out) {
  int idx = blockIdx.x * 256 + threadIdx.x;  // 0..4095
  int g = idx >> 6, o = idx & 63;
  float inv = 1.f / fmaxf((float)(gstart[g + 1] - gstart[g]), 1.f);
  float acc = bl[o];
  for (int k = 0; k < 64; ++k) acc += pooled[g * 64 + k] * inv * Wl[k * 64 + o];
  out[idx] = acc;
}

// ============================ launch ============================

extern "C" void kernel_launch(void* const* d_in, const int* in_sizes, int n_in,
                              void* d_out, int out_size, void* d_ws, size_t ws_size,
                              hipStream_t stream) {
  const float* x = (const float*)d_in[0];
  const int* ei = (const int*)d_in[1];     // int32, [2, NE]
  const int* batch = (const int*)d_in[2];  // int32, sorted
  const float* W1a = (const float*)d_in[3];
  const float* b1a = (const float*)d_in[4];
  const float* W2a = (const float*)d_in[5];
  const float* b2a = (const float*)d_in[6];
  const float* W1b = (const float*)d_in[7];
  const float* b1b = (const float*)d_in[8];
  const float* W2b = (const float*)d_in[9];
  const float* b2b = (const float*)d_in[10];
  const float* Wl = (const float*)d_in[11];
  const float* bl = (const float*)d_in[12];
  float* out = (float*)d_out;

  char* p = (char*)d_ws;
  auto alloc = [&](size_t bytes) {
    char* r = p;
    p += (bytes + 255) & ~(size_t)255;
    return r;
  };
  int* deg = (int*)alloc((NN + 1) * sizeof(int));
  int* rowptr = (int*)alloc((NN + 1) * sizeof(int));
  int* cursor = (int*)alloc(NN * sizeof(int));
  int* bsums = (int*)alloc(256 * sizeof(int));
  int* gstart = (int*)alloc((NG + 1) * sizeof(int));
  int* srcs = (int*)alloc((size_t)NE * sizeof(int));
  float* ab = (float*)alloc((size_t)NN * 128 * sizeof(float));
  float* hbuf = (float*)alloc((size_t)NN * 64 * sizeof(float));  // agg and h alias
  float* pooled = (float*)alloc(NG * 64 * sizeof(float));

  hipMemsetAsync(deg, 0, (NN + 1) * sizeof(int), stream);
  hipMemsetAsync(pooled, 0, NG * 64 * sizeof(float), stream);

  hist_kernel<<<(NE + 255) / 256, 256, 0, stream>>>(ei, deg);
  scan1_kernel<<<196, 256, 0, stream>>>(deg, rowptr, bsums);
  scan2_kernel<<<1, 256, 0, stream>>>(bsums, 196);
  scan3_kernel<<<196, 256, 0, stream>>>(rowptr, bsums, cursor);
  scatter_xcd<<<1024, 256, 0, stream>>>(ei, cursor, srcs);
  gstart_kernel<<<1, 128, 0, stream>>>(batch, gstart);

  int tb = (NN + 63) / 64;  // 782
  // layer 1
  transform_dual<<<tb, 256, 0, stream>>>(x, W1a, ab);
  edge_agg<<<(NN + 3) / 4, 256, 0, stream>>>(ab, rowptr, srcs, b1a, hbuf);
  transform_single<<<tb, 256, 0, stream>>>(hbuf, W2a, b2a, deg, hbuf);
  // layer 2
  transform_dual<<<tb, 256, 0, stream>>>(hbuf, W1b, ab);
  edge_agg<<<(NN + 3) / 4, 256, 0, stream>>>(ab, rowptr, srcs, b1b, hbuf);
  transform_single<<<tb, 256, 0, stream>>>(hbuf, W2b, b2b, deg, hbuf);
  // pool + head
  pool_kernel<<<NG * 4, 256, 0, stream>>>(hbuf, gstart, pooled);
  final_kernel<<<16, 256, 0, stream>>>(pooled, gstart, Wl, bl, out);
}